// Round 5
// baseline (101906.696 us; speedup 1.0000x reference)
//
#include <hip/hip_runtime.h>
#include <hip/hip_fp16.h>
#include <stdint.h>

// LSTM_29042568856007: B=64, T=4096, D=256, H=256.
// Round 5: 1 WG/batch, f16 weights + v_dot2_f32_f16 (round 4 base) plus:
//  (a) NV=8 W_hh chunks (k<64) permanent in VGPRs. Requires
//      __launch_bounds__(1024,4) -> 1 block/CU -> 128-VGPR cap (round 3's
//      spill was the 2-block/64-VGPR default). Streamed W_hh: 512->384 KB/step.
//  (b) x-gate pass dissolved into the recurrence: each step computes 4 of 32
//      W_ih chunks for the NEXT group, accumulating in registers (xprev/xnext).
//      No xg LDS buffer, no x-pass burst -> W_ih stream overlaps barrier gaps.
// Stream/step: 384 + 64 = 448 KB @ ~50-64 B/cyc/CU.

#define LSTM_B 64
#define LSTM_T 4096
#define LSTM_D 256
#define LSTM_H 256
#define NX 8
#define NG (LSTM_T / NX)
#define NV 8            // W_hh uint4-chunks resident in VGPRs (32 VGPRs)

typedef __attribute__((ext_vector_type(2))) _Float16 half2_t;

static __device__ __forceinline__ float dot2(uint32_t w, uint32_t a, float acc) {
#if __has_builtin(__builtin_amdgcn_fdot2)
    return __builtin_amdgcn_fdot2(__builtin_bit_cast(half2_t, w),
                                  __builtin_bit_cast(half2_t, a), acc, false);
#else
    __half2 hw = __builtin_bit_cast(__half2, w);
    __half2 ha = __builtin_bit_cast(__half2, a);
    acc = fmaf(__low2float(hw), __low2float(ha), acc);
    acc = fmaf(__high2float(hw), __high2float(ha), acc);
    return acc;
#endif
}

// ws: uint4 Wp[64][1024] (k4, r), 1 MiB packed f16 pairs.
//   k4 in [0,32): W_ih, k = 8*k4 + ...; k4 in [32,64): W_hh.
__global__ __launch_bounds__(256) void prep_weights(
    const float* __restrict__ W_ih, const float* __restrict__ W_hh,
    uint32_t* __restrict__ Wp)
{
    int idx = blockIdx.x * blockDim.x + threadIdx.x;  // uint index [0, 262144)
    if (idx >= 64 * 1024 * 4) return;
    int e  = idx & 3;
    int r  = (idx >> 2) & 1023;
    int k4 = idx >> 12;
    int k  = ((k4 & 31) << 3) + (e << 1);
    const float* W = (k4 < 32) ? W_ih : W_hh;
    uint32_t lo = (uint32_t)__half_as_ushort(__float2half(W[r * 256 + k]));
    uint32_t hi = (uint32_t)__half_as_ushort(__float2half(W[r * 256 + k + 1]));
    Wp[idx] = lo | (hi << 16);
}

static __device__ __forceinline__ float sigmoidf_(float x) {
    return 1.0f / (1.0f + __expf(-x));
}
static __device__ __forceinline__ float tanhf_(float x) {
    float ax = fabsf(x);
    float e  = __expf(-2.0f * ax);
    float t  = (1.0f - e) / (1.0f + e);
    return copysignf(t, x);
}

static __device__ __forceinline__ uint32_t packf16(float2 v) {
    __half2 p = __floats2half2_rn(v.x, v.y);
    return __builtin_bit_cast(uint32_t, p);
}

__global__ __launch_bounds__(1024, 4) void lstm_r5(
    const float* __restrict__ xs,     // [B, T, D] fp32
    const float* __restrict__ bias_g, // [4H]
    const uint4* __restrict__ Wp,     // [64][1024] f16-pair octets
    float* __restrict__ out)          // h[B,H] then c[B,H]
{
    __shared__ __align__(16) uint32_t x_u[NX * 128];   // 4 KiB  f16 x, one group
    __shared__ __align__(16) uint32_t h_u[128];        // 512 B  f16 h
    __shared__ __align__(16) float    g_s[1024];       // 4 KiB  gates

    const int tid = threadIdx.x;   // gate row r = tid
    const int b   = blockIdx.x;    // batch element

    const float bias = bias_g[tid];
    const float* xrow = xs + (size_t)b * LSTM_T * LSTM_D;

    const uint4* Wih  = Wp + tid;               // + (k4<<10), k4 in [0,32)
    const uint4* Whh  = Wp + (32 << 10) + tid;  // + (k4<<10), k4 in [0,32)
    const uint4* x_u4 = (const uint4*)x_u;
    const uint4* h_u4 = (const uint4*)h_u;

    // permanent W_hh chunks (k in [0, 8*NV)) — 32 VGPRs
    uint4 wperm[NV];
    #pragma unroll
    for (int i = 0; i < NV; ++i) wperm[i] = Whh[i << 10];

    if (tid < 128) h_u[tid] = 0u;
    float c = 0.0f, hlast = 0.0f;

    // ---- prologue: stage x group 0, prefetch group 1, x-pass for group 0 ----
    float2 xpre = ((const float2*)xrow)[tid];          // group 0
    x_u[tid] = packf16(xpre);
    xpre = ((const float2*)xrow)[1024 + tid];          // group 1
    __syncthreads();   // x_u(group0) + h_u visible

    float xnext[NX], xprev[NX];
    #pragma unroll
    for (int s = 0; s < NX; ++s) xnext[s] = bias;
    #pragma unroll 4
    for (int k4 = 0; k4 < 32; ++k4) {
        uint4 w = Wih[k4 << 10];
        #pragma unroll
        for (int tt = 0; tt < NX; ++tt) {
            uint4 xa = x_u4[tt * 32 + k4];   // wave-uniform -> broadcast
            float s0 = xnext[tt];
            s0 = dot2(w.x, xa.x, s0);
            s0 = dot2(w.y, xa.y, s0);
            s0 = dot2(w.z, xa.z, s0);
            s0 = dot2(w.w, xa.w, s0);
            xnext[tt] = s0;
        }
    }
    __syncthreads();   // prologue x_u reads done before tg=0 overwrites x_u

    #pragma unroll 1
    for (int tg = 0; tg < NG; ++tg) {
        // hand over x-gates; re-init accumulators for group tg+1
        #pragma unroll
        for (int s = 0; s < NX; ++s) { xprev[s] = xnext[s]; xnext[s] = bias; }
        // stage x for group tg+1; prefetch group tg+2 (clamped)
        x_u[tid] = packf16(xpre);
        int ng = (tg + 2 < NG) ? tg + 2 : NG - 1;
        xpre = ((const float2*)(xrow + (size_t)ng * NX * LSTM_D))[tid];
        __syncthreads();   // bar T: x_u ready

        #pragma unroll 1
        for (int s = 0; s < NX; ++s) {
            float acc0 = xprev[s], acc1 = 0.0f;

            // resident W_hh chunks
            #pragma unroll
            for (int i = 0; i < NV; ++i) {
                uint4 ha = h_u4[i];
                acc0 = dot2(wperm[i].x, ha.x, acc0);
                acc1 = dot2(wperm[i].y, ha.y, acc1);
                acc0 = dot2(wperm[i].z, ha.z, acc0);
                acc1 = dot2(wperm[i].w, ha.w, acc1);
            }
            // streamed W_hh chunks
            #pragma unroll 4
            for (int k4 = NV; k4 < 32; ++k4) {
                uint4 w  = Whh[k4 << 10];
                uint4 ha = h_u4[k4];
                acc0 = dot2(w.x, ha.x, acc0);
                acc1 = dot2(w.y, ha.y, acc1);
                acc0 = dot2(w.z, ha.z, acc0);
                acc1 = dot2(w.w, ha.w, acc1);
            }
            // interleaved x-chunks for group tg+1 (k4x = 4s .. 4s+3)
            #pragma unroll
            for (int j = 0; j < 4; ++j) {
                int k4x = 4 * s + j;
                uint4 w = Wih[k4x << 10];
                #pragma unroll
                for (int tt = 0; tt < NX; ++tt) {
                    uint4 xa = x_u4[tt * 32 + k4x];
                    float s0 = xnext[tt];
                    s0 = dot2(w.x, xa.x, s0);
                    s0 = dot2(w.y, xa.y, s0);
                    s0 = dot2(w.z, xa.z, s0);
                    s0 = dot2(w.w, xa.w, s0);
                    xnext[tt] = s0;
                }
            }
            g_s[tid] = acc0 + acc1;
            __syncthreads();   // bar G: gates ready

            if (tid < LSTM_H) {
                float gi = g_s[tid];
                float gf = g_s[tid + 256];
                float gg = g_s[tid + 512];
                float go = g_s[tid + 768];
                c = sigmoidf_(gf) * c + sigmoidf_(gi) * tanhf_(gg);
                hlast = sigmoidf_(go) * tanhf_(c);
                uint32_t mine = (uint32_t)__half_as_ushort(__float2half(hlast));
                uint32_t partner = (uint32_t)__shfl_xor((int)mine, 1, 64);
                if ((tid & 1) == 0) h_u[tid >> 1] = (mine & 0xffffu) | (partner << 16);
            }
            __syncthreads();   // bar H: h_{t+1} visible
        }
    }

    if (tid < LSTM_H) {
        out[b * LSTM_H + tid]                   = hlast;  // h_T
        out[LSTM_B * LSTM_H + b * LSTM_H + tid] = c;      // c_T
    }
}

extern "C" void kernel_launch(void* const* d_in, const int* in_sizes, int n_in,
                              void* d_out, int out_size, void* d_ws, size_t ws_size,
                              hipStream_t stream) {
    const float* xs   = (const float*)d_in[0];  // [64,4096,256]
    const float* W_ih = (const float*)d_in[1];  // [1024,256]
    const float* W_hh = (const float*)d_in[2];  // [1024,256]
    const float* b    = (const float*)d_in[3];  // [1024]
    float* out = (float*)d_out;
    uint32_t* Wp = (uint32_t*)d_ws;             // 1 MiB packed f16 weights

    prep_weights<<<1024, 256, 0, stream>>>(W_ih, W_hh, Wp);
    lstm_r5<<<LSTM_B, 1024, 0, stream>>>(xs, b, (const uint4*)Wp, out);
}